// Round 4
// baseline (650.641 us; speedup 1.0000x reference)
//
#include <hip/hip_runtime.h>

#define NTOK 197
#define C 768
#define C3 2304
#define BK 32
#define PK 40     // fallback LDS pitch
#define NT 13
#define CPAD 772  // cls LDS pitch (floats)
#define AWP 200   // a_weight LDS pitch (ushorts)

typedef __attribute__((ext_vector_type(4))) float f32x4;
typedef __attribute__((ext_vector_type(8))) short bf16x8;
typedef unsigned int u32;

__device__ __forceinline__ ushort f2bf(float f){
  uint u = __float_as_uint(f);
  u += 0x7fffu + ((u >> 16) & 1u);   // RNE
  return (ushort)(u >> 16);
}
__device__ __forceinline__ uint pack2(float a, float b){
  return (uint)f2bf(a) | ((uint)f2bf(b) << 16);
}
__device__ __forceinline__ float bfu2f(uint u){ return __uint_as_float(u << 16); }

__device__ __forceinline__ void glds16(ushort* lds, const ushort* gsrc){
  __builtin_amdgcn_global_load_lds((const __attribute__((address_space(1))) u32*)gsrc,
                                   (__attribute__((address_space(3))) u32*)lds, 16, 0, 0);
}

// ---------------------------------------------------------------------------
// cvt_all: weight (442368 f4) then x (4841472 f4) -> bf16, one dispatch
// ---------------------------------------------------------------------------
#define N4_W 442368
#define N4_X 4841472
__global__ void cvt_all(const float* __restrict__ w, const float* __restrict__ x,
                        ushort* __restrict__ wbf, ushort* __restrict__ xbf)
{
  const int n4 = N4_W + N4_X;
  int stride = gridDim.x * blockDim.x;
  for (int i = blockIdx.x*blockDim.x + threadIdx.x; i < n4; i += stride){
    const float4* src; ushort4* dst;
    if (i < N4_W){ src = reinterpret_cast<const float4*>(w) + i;
                   dst = reinterpret_cast<ushort4*>(wbf) + i; }
    else         { src = reinterpret_cast<const float4*>(x) + (i - N4_W);
                   dst = reinterpret_cast<ushort4*>(xbf) + (i - N4_W); }
    float4 v = *src;
    ushort4 o;
    o.x = f2bf(v.x); o.y = f2bf(v.y); o.z = f2bf(v.z); o.w = f2bf(v.w);
    *dst = o;
  }
}

// ---------------------------------------------------------------------------
// conv3: routing conv1d on CLS token, fp32 a_weight staged->bf16 LDS coalesced.
// grid (36 oc-chunks, 16 b), block 256 = 64 o x 4 k-parts.
// ---------------------------------------------------------------------------
__global__ __launch_bounds__(256)
void conv3(const float* __restrict__ x, const float* __restrict__ aw,
           const float* __restrict__ ab, float* __restrict__ s_ws)
{
  __shared__ __align__(16) float  cls[10][CPAD];   // rows 0,9 zero pad
  __shared__ __align__(16) ushort awt[64*AWP];     // 64 o x 192 cols (bf16)
  __shared__ float partial[64][4][9];
  const int oc = blockIdx.x, b = blockIdx.y, tid = threadIdx.x;

  for (int task = tid; task < 1920; task += 256){
    int row = task / 192, c4 = task % 192;
    float4 v = {0.f,0.f,0.f,0.f};
    if (row >= 1 && row <= 8)
      v = *reinterpret_cast<const float4*>(x + (size_t)(b*8 + row - 1)*NTOK*C + c4*4);
    *reinterpret_cast<float4*>(&cls[row][c4*4]) = v;
  }

  const int o_l = tid >> 2, part = tid & 3;
  float acc[8];
  #pragma unroll
  for (int t=0;t<8;t++) acc[t]=0.f;

  for (int it = 0; it < 12; ++it){
    const int i0 = it*64;
    // stage 64 rows x 192 floats of a_weight -> bf16 LDS (3072 f4-chunk tasks)
    #pragma unroll
    for (int j = 0; j < 12; ++j){
      int task = tid + j*256;
      int r = task / 48, c4 = task % 48;
      float4 v = *reinterpret_cast<const float4*>(aw + (size_t)(oc*64 + r)*C3 + i0*3 + c4*4);
      uint2 pk; pk.x = pack2(v.x, v.y); pk.y = pack2(v.z, v.w);
      *reinterpret_cast<uint2*>(&awt[r*AWP + c4*4]) = pk;
    }
    __syncthreads();

    #pragma unroll
    for (int qq = 0; qq < 4; ++qq){
      const int i_loc = part*16 + qq*4;
      const int ib = i0 + i_loc;
      float4 cv[10];
      #pragma unroll
      for (int t=0;t<10;t++) cv[t] = *reinterpret_cast<const float4*>(&cls[t][ib]);
      float wv[4][3];
      #pragma unroll
      for (int e=0;e<4;e++){
        #pragma unroll
        for (int dk=0;dk<3;dk++)
          wv[e][dk] = bfu2f((uint)awt[o_l*AWP + (i_loc+e)*3 + dk]);
      }
      #pragma unroll
      for (int e=0;e<4;e++){
        #pragma unroll
        for (int dk=0;dk<3;dk++){
          const float wf = wv[e][dk];
          #pragma unroll
          for (int t=0;t<8;t++){
            const float* cp = reinterpret_cast<const float*>(&cv[t+dk]);
            acc[t] += wf * cp[e];
          }
        }
      }
    }
    __syncthreads();
  }

  #pragma unroll
  for (int t=0;t<8;t++) partial[o_l][part][t] = acc[t];
  __syncthreads();

  for (int idx = tid; idx < 512; idx += 256){
    int o = idx >> 3, t = idx & 7;
    float v = partial[o][0][t] + partial[o][1][t]
            + partial[o][2][t] + partial[o][3][t]
            + ab[oc*64 + o] + 1.0f;
    s_ws[(size_t)(b*8 + t)*C3 + oc*64 + o] = v;
  }
}

// ---------------------------------------------------------------------------
// gemm3: per (bt,g,mt): Out = (W_g .* s[bt,g,:]) x X[bt]^T, fused scale on A.
// Tile 128x208, BK=32, 4 waves x (2 m-frags x 13 n-frags).
// B staged via global_load_lds from pre-converted xbf; A scaled in regs.
// ---------------------------------------------------------------------------
__global__ __launch_bounds__(256)
void gemm3(const ushort* __restrict__ wbf, const ushort* __restrict__ xbf,
           const float* __restrict__ s_ws, const float* __restrict__ bias,
           float* __restrict__ out)
{
  __shared__ __align__(16) ushort A_lds[128*BK];   // scaled W  [128][32]
  __shared__ __align__(16) ushort B_lds[208*BK];   // X tokens  [208][32]

  // bijective XCD swizzle: 2304 blocks, 288/XCD -> 16 consecutive bt per XCD
  const int lid  = blockIdx.x;
  const int work = (lid & 7)*288 + (lid >> 3);
  const int bt   = work / 18;
  const int rem  = work - bt*18;
  const int g    = rem / 6;
  const int mt   = rem - g*6;

  const int tid = threadIdx.x, w = tid >> 6, lane = tid & 63;
  const int l15 = lane & 15, lq = lane >> 4;

  const float*  srow = s_ws + (size_t)bt*C3 + (size_t)g*C;
  const ushort* Ap   = wbf + ((size_t)g*C + (size_t)mt*128)*C;
  const ushort* xb   = xbf + (size_t)bt*NTOK*C;

  // A staging assignment: thread -> row (tid>>1), 16-ushort chunk (tid&1)
  const int arow  = tid >> 1;
  const int acol  = (tid & 1) * 16;

  f32x4 acc[2][13];
  #pragma unroll
  for (int i=0;i<2;i++)
    #pragma unroll
    for (int j=0;j<13;j++) acc[i][j] = (f32x4){0.f,0.f,0.f,0.f};

  for (int k0 = 0; k0 < C; k0 += BK){
    // ---- stage A: scaled W -> bf16 LDS (VALU path)
    {
      const ushort* wp = Ap + (size_t)arow*C + k0 + acol;
      uint4 w0 = *reinterpret_cast<const uint4*>(wp);
      uint4 w1 = *reinterpret_cast<const uint4*>(wp + 8);
      const float* sp = srow + k0 + acol;
      float4 s0 = *reinterpret_cast<const float4*>(sp);
      float4 s1 = *reinterpret_cast<const float4*>(sp+4);
      float4 s2 = *reinterpret_cast<const float4*>(sp+8);
      float4 s3 = *reinterpret_cast<const float4*>(sp+12);
      uint4 o0, o1;
      o0.x = pack2(bfu2f(w0.x & 0xffffu)*s0.x, bfu2f(w0.x >> 16)*s0.y);
      o0.y = pack2(bfu2f(w0.y & 0xffffu)*s0.z, bfu2f(w0.y >> 16)*s0.w);
      o0.z = pack2(bfu2f(w0.z & 0xffffu)*s1.x, bfu2f(w0.z >> 16)*s1.y);
      o0.w = pack2(bfu2f(w0.w & 0xffffu)*s1.z, bfu2f(w0.w >> 16)*s1.w);
      o1.x = pack2(bfu2f(w1.x & 0xffffu)*s2.x, bfu2f(w1.x >> 16)*s2.y);
      o1.y = pack2(bfu2f(w1.y & 0xffffu)*s2.z, bfu2f(w1.y >> 16)*s2.w);
      o1.z = pack2(bfu2f(w1.z & 0xffffu)*s3.x, bfu2f(w1.z >> 16)*s3.y);
      o1.w = pack2(bfu2f(w1.w & 0xffffu)*s3.z, bfu2f(w1.w >> 16)*s3.w);
      *reinterpret_cast<uint4*>(&A_lds[arow*BK + acol    ]) = o0;
      *reinterpret_cast<uint4*>(&A_lds[arow*BK + acol + 8]) = o1;
    }
    // ---- stage B: 13 wave-issues of global_load_lds (16 rows each)
    for (int e = w; e < 13; e += 4){
      glds16(&B_lds[e*512], xb + (size_t)(e*16 + (lane>>2))*C + k0 + (lane&3)*8);
    }
    __syncthreads();

    bf16x8 a0 = *reinterpret_cast<const bf16x8*>(&A_lds[(w*32      + l15)*BK + lq*8]);
    bf16x8 a1 = *reinterpret_cast<const bf16x8*>(&A_lds[(w*32 + 16 + l15)*BK + lq*8]);
    #pragma unroll
    for (int nf=0; nf<13; nf++){
      bf16x8 b = *reinterpret_cast<const bf16x8*>(&B_lds[(nf*16 + l15)*BK + lq*8]);
      acc[0][nf] = __builtin_amdgcn_mfma_f32_16x16x32_bf16(a0, b, acc[0][nf], 0, 0, 0);
      acc[1][nf] = __builtin_amdgcn_mfma_f32_16x16x32_bf16(a1, b, acc[1][nf], 0, 0, 0);
    }
    __syncthreads();
  }

  // ---- epilogue
  #pragma unroll
  for (int mf=0; mf<2; mf++){
    const int o0 = mt*128 + w*32 + mf*16 + lq*4;
    float bs[4];
    #pragma unroll
    for (int r=0;r<4;r++)
      bs[r] = bias[g*C + o0 + r] * srow[o0 + r];
    #pragma unroll
    for (int nf=0; nf<13; nf++){
      int n = nf*16 + l15;
      if (n < NTOK){
        #pragma unroll
        for (int r=0;r<4;r++)
          out[((size_t)bt*C3 + g*C + o0 + r)*NTOK + n] = acc[mf][nf][r] + bs[r];
      }
    }
  }
}

// ---------------------------------------------------------------------------
// fallback: single fused GEMM reading fp32 x (needs only s_ws + wbf in ws)
// ---------------------------------------------------------------------------
__global__ __launch_bounds__(512)
void gemm_fb(const float* __restrict__ x, const ushort* __restrict__ wbf,
             const float* __restrict__ s_ws, const float* __restrict__ bias,
             float* __restrict__ out)
{
  __shared__ __align__(16) ushort A_lds[128*PK];
  __shared__ __align__(16) ushort B_lds[208*PK];
  const int ot  = blockIdx.x;
  const int g   = blockIdx.y;
  const int bt  = blockIdx.z;
  const int tid = threadIdx.x;
  const int w = tid >> 6, lane = tid & 63;
  const int l15 = lane & 15, lq = lane >> 4;

  const float*  srow  = s_ws + (size_t)bt*C3 + (size_t)g*C;
  const ushort* wrow  = wbf + ((size_t)g*C + (size_t)ot*128)*C;
  const float*  xrow  = x   + (size_t)bt*NTOK*C;

  f32x4 acc[NT];
  #pragma unroll
  for (int j=0;j<NT;j++) acc[j] = (f32x4){0.f,0.f,0.f,0.f};

  const int ar = tid >> 2, ac = tid & 3;

  for (int k0 = 0; k0 < C; k0 += BK){
    {
      uint4 wv = *reinterpret_cast<const uint4*>(wrow + (size_t)ar*C + k0 + ac*8);
      const float* sv = srow + k0 + ac*8;
      float4 s0 = *reinterpret_cast<const float4*>(sv);
      float4 s1 = *reinterpret_cast<const float4*>(sv+4);
      uint4 av;
      av.x = pack2(bfu2f(wv.x & 0xffffu)*s0.x, bfu2f(wv.x >> 16)*s0.y);
      av.y = pack2(bfu2f(wv.y & 0xffffu)*s0.z, bfu2f(wv.y >> 16)*s0.w);
      av.z = pack2(bfu2f(wv.z & 0xffffu)*s1.x, bfu2f(wv.z >> 16)*s1.y);
      av.w = pack2(bfu2f(wv.w & 0xffffu)*s1.z, bfu2f(wv.w >> 16)*s1.w);
      *reinterpret_cast<uint4*>(&A_lds[ar*PK + ac*8]) = av;
    }
    #pragma unroll
    for (int it = 0; it < 2; ++it){
      int task = tid + it*512;
      if (task < 832){
        int r = task >> 2, cc = task & 3;
        uint4 bv = {0u,0u,0u,0u};
        if (r < NTOK){
          const float* p = xrow + (size_t)r*C + k0 + cc*8;
          float4 lo = *reinterpret_cast<const float4*>(p);
          float4 hi = *reinterpret_cast<const float4*>(p+4);
          bv.x = pack2(lo.x, lo.y); bv.y = pack2(lo.z, lo.w);
          bv.z = pack2(hi.x, hi.y); bv.w = pack2(hi.z, hi.w);
        }
        *reinterpret_cast<uint4*>(&B_lds[r*PK + cc*8]) = bv;
      }
    }
    __syncthreads();

    bf16x8 a = *reinterpret_cast<const bf16x8*>(&A_lds[(w*16 + l15)*PK + lq*8]);
    #pragma unroll
    for (int j=0;j<NT;j++){
      bf16x8 b = *reinterpret_cast<const bf16x8*>(&B_lds[(j*16 + l15)*PK + lq*8]);
      acc[j] = __builtin_amdgcn_mfma_f32_16x16x32_bf16(a, b, acc[j], 0, 0, 0);
    }
    __syncthreads();
  }

  const int obase = ot*128 + w*16 + lq*4;
  float bs[4];
  #pragma unroll
  for (int r=0;r<4;r++)
    bs[r] = bias[g*C + obase + r] * srow[obase + r];
  #pragma unroll
  for (int j=0;j<NT;j++){
    int n = j*16 + l15;
    if (n < NTOK){
      #pragma unroll
      for (int r=0;r<4;r++)
        out[((size_t)bt*C3 + g*C + obase + r)*NTOK + n] = acc[j][r] + bs[r];
    }
  }
}

__global__ void cvt_w_only(const float* __restrict__ in, ushort* __restrict__ outp, int n4)
{
  int stride = gridDim.x * blockDim.x;
  for (int i = blockIdx.x*blockDim.x + threadIdx.x; i < n4; i += stride){
    float4 v = reinterpret_cast<const float4*>(in)[i];
    ushort4 o;
    o.x = f2bf(v.x); o.y = f2bf(v.y); o.z = f2bf(v.z); o.w = f2bf(v.w);
    reinterpret_cast<ushort4*>(outp)[i] = o;
  }
}

// ---------------------------------------------------------------------------
extern "C" void kernel_launch(void* const* d_in, const int* in_sizes, int n_in,
                              void* d_out, int out_size, void* d_ws, size_t ws_size,
                              hipStream_t stream)
{
  const float* x        = (const float*)d_in[0];
  const float* a_weight = (const float*)d_in[1];
  const float* a_bias   = (const float*)d_in[2];
  const float* weight   = (const float*)d_in[3];
  const float* bias     = (const float*)d_in[4];
  float* out = (float*)d_out;

  char* ws = (char*)d_ws;
  float*  s_ws = (float*)ws;                 // 1,179,648 B
  ushort* wbf  = (ushort*)(ws + 1179648);    // 3,538,944 B
  ushort* xbf  = (ushort*)(ws + 4718592);    // 38,731,776 B (+32 KB OOB slack beyond)
  const size_t NEED_FULL = 43483136;         // includes OOB-read slack

  if (ws_size >= NEED_FULL){
    cvt_all<<<dim3(2048), 256, 0, stream>>>(weight, x, wbf, xbf);
    conv3<<<dim3(36,16), 256, 0, stream>>>(x, a_weight, a_bias, s_ws);
    gemm3<<<dim3(2304), 256, 0, stream>>>(wbf, xbf, s_ws, bias, out);
  } else {
    cvt_w_only<<<dim3(1728), 256, 0, stream>>>(weight, wbf, 442368);
    conv3<<<dim3(36,16), 256, 0, stream>>>(x, a_weight, a_bias, s_ws);
    gemm_fb<<<dim3(6,3,128), 512, 0, stream>>>(x, wbf, s_ws, bias, out);
  }
}

// Round 5
// 491.649 us; speedup vs baseline: 1.3234x; 1.3234x over previous
//
#include <hip/hip_runtime.h>

#define NTOK 197
#define C 768
#define C3 2304
#define BK 32
#define PK 40     // fallback LDS pitch
#define NT 13
#define CPAD 772  // fallback cls pitch
#define AWP 200   // fallback aw pitch

typedef __attribute__((ext_vector_type(4))) float f32x4;
typedef __attribute__((ext_vector_type(8))) short bf16x8;
typedef unsigned int u32;

__device__ __forceinline__ ushort f2bf(float f){
  uint u = __float_as_uint(f);
  u += 0x7fffu + ((u >> 16) & 1u);   // RNE
  return (ushort)(u >> 16);
}
__device__ __forceinline__ uint pack2(float a, float b){
  return (uint)f2bf(a) | ((uint)f2bf(b) << 16);
}
__device__ __forceinline__ float bfu2f(uint u){ return __uint_as_float(u << 16); }

__device__ __forceinline__ void glds16(ushort* lds, const ushort* gsrc){
  __builtin_amdgcn_global_load_lds((const __attribute__((address_space(1))) u32*)gsrc,
                                   (__attribute__((address_space(3))) u32*)lds, 16, 0, 0);
}

// ---------------------------------------------------------------------------
// cvt_all: weight then x -> bf16, branch-free grid-stride
// ---------------------------------------------------------------------------
#define N4_W 442368
#define N4_X 4841472
__global__ __launch_bounds__(256)
void cvt_all(const float* __restrict__ w, const float* __restrict__ x,
             ushort* __restrict__ wbf, ushort* __restrict__ xbf)
{
  const int tid0 = blockIdx.x*256 + threadIdx.x;
  const int stride = gridDim.x*256;
  for (int i = tid0; i < N4_W; i += stride){
    float4 v = reinterpret_cast<const float4*>(w)[i];
    ushort4 o; o.x=f2bf(v.x); o.y=f2bf(v.y); o.z=f2bf(v.z); o.w=f2bf(v.w);
    reinterpret_cast<ushort4*>(wbf)[i] = o;
  }
  for (int i = tid0; i < N4_X; i += stride){
    float4 v = reinterpret_cast<const float4*>(x)[i];
    ushort4 o; o.x=f2bf(v.x); o.y=f2bf(v.y); o.z=f2bf(v.z); o.w=f2bf(v.w);
    reinterpret_cast<ushort4*>(xbf)[i] = o;
  }
}

// ---------------------------------------------------------------------------
// conv_part: split-K routing conv. grid (36 oc, 12 kp), block 256 = 64 o x 4 bq.
// a_weight read exactly once across the whole grid.
// partial[kp][bt][o] = sum over k-slice of aw[o][k][dk]*cls[b][t+dk][k]
// ---------------------------------------------------------------------------
__global__ __launch_bounds__(256)
void conv_part(const float* __restrict__ x, const float* __restrict__ aw,
               float* __restrict__ partial)
{
  __shared__ __align__(16) float  cls[16][10][68];   // [b][t'][k], t'=t+1, pad 68
  __shared__ __align__(16) ushort awt[64*64*4];      // [o][k][(w0,w1,w2,pad)]
  const int oc = blockIdx.x, kp = blockIdx.y, tid = threadIdx.x;
  const int k0 = kp*64;

  // stage cls: 2560 float4 tasks (b, t', 16 chunks of 4 floats)
  for (int task = tid; task < 2560; task += 256){
    int b = task / 160, rem = task % 160;
    int tp = rem / 16, c4 = rem % 16;
    float4 v = {0.f,0.f,0.f,0.f};
    if (tp >= 1 && tp <= 8)
      v = *reinterpret_cast<const float4*>(x + (size_t)(b*8 + tp - 1)*NTOK*C + k0 + c4*4);
    *reinterpret_cast<float4*>(&cls[b][tp][c4*4]) = v;
  }
  // stage awt: 1024 tasks (o row, kc chunk of 4 k); 12 floats -> 4 padded bf16 triples
  for (int task = tid; task < 1024; task += 256){
    int r = task >> 4, kc = task & 15;
    const float* p = aw + (size_t)(oc*64 + r)*2304 + (size_t)(k0 + kc*4)*3;
    float4 f0 = *reinterpret_cast<const float4*>(p);
    float4 f1 = *reinterpret_cast<const float4*>(p+4);
    float4 f2 = *reinterpret_cast<const float4*>(p+8);
    float f[12] = {f0.x,f0.y,f0.z,f0.w, f1.x,f1.y,f1.z,f1.w, f2.x,f2.y,f2.z,f2.w};
    uint4 o0, o1;
    o0.x = pack2(f[0], f[1]);  o0.y = (uint)f2bf(f[2]);
    o0.z = pack2(f[3], f[4]);  o0.w = (uint)f2bf(f[5]);
    o1.x = pack2(f[6], f[7]);  o1.y = (uint)f2bf(f[8]);
    o1.z = pack2(f[9], f[10]); o1.w = (uint)f2bf(f[11]);
    uint4* dst = reinterpret_cast<uint4*>(&awt[(r*64 + kc*4)*4]);
    dst[0] = o0; dst[1] = o1;
  }
  __syncthreads();

  const int o_l = tid >> 2, bq = tid & 3;
  float acc[8][4];
  #pragma unroll
  for (int t=0;t<8;t++)
    #pragma unroll
    for (int bi=0;bi<4;bi++) acc[t][bi]=0.f;

  #pragma unroll 1
  for (int kc = 0; kc < 16; ++kc){
    // aw for 4 k-entries (broadcast across the 4 bq lanes)
    const uint4* ap = reinterpret_cast<const uint4*>(&awt[(o_l*64 + kc*4)*4]);
    uint4 aw0 = ap[0], aw1 = ap[1];
    float wv[4][3];
    wv[0][0]=bfu2f(aw0.x&0xffffu); wv[0][1]=bfu2f(aw0.x>>16); wv[0][2]=bfu2f(aw0.y&0xffffu);
    wv[1][0]=bfu2f(aw0.z&0xffffu); wv[1][1]=bfu2f(aw0.z>>16); wv[1][2]=bfu2f(aw0.w&0xffffu);
    wv[2][0]=bfu2f(aw1.x&0xffffu); wv[2][1]=bfu2f(aw1.x>>16); wv[2][2]=bfu2f(aw1.y&0xffffu);
    wv[3][0]=bfu2f(aw1.z&0xffffu); wv[3][1]=bfu2f(aw1.z>>16); wv[3][2]=bfu2f(aw1.w&0xffffu);
    #pragma unroll
    for (int bi=0; bi<4; ++bi){
      const int b = bq + 4*bi;
      float4 cv[10];
      #pragma unroll
      for (int tp=0; tp<10; tp++)
        cv[tp] = *reinterpret_cast<const float4*>(&cls[b][tp][kc*4]);
      #pragma unroll
      for (int t=0;t<8;t++){
        #pragma unroll
        for (int dk=0;dk<3;dk++){
          const float* cp = reinterpret_cast<const float*>(&cv[t+dk]);
          #pragma unroll
          for (int e=0;e<4;e++)
            acc[t][bi] += wv[e][dk] * cp[e];
        }
      }
    }
  }

  // write partials: partial[kp][b*8+t][oc*64+o_l]
  #pragma unroll
  for (int bi=0;bi<4;bi++){
    const int b = bq + 4*bi;
    #pragma unroll
    for (int t=0;t<8;t++)
      partial[((size_t)kp*128 + b*8 + t)*C3 + oc*64 + o_l] = acc[t][bi];
  }
}

// ---------------------------------------------------------------------------
// conv_reduce: s_ws[bt][o] = sum_kp partial[kp][bt][o] + ab[o] + 1
// grid (9, 128), block 256
// ---------------------------------------------------------------------------
__global__ __launch_bounds__(256)
void conv_reduce(const float* __restrict__ partial, const float* __restrict__ ab,
                 float* __restrict__ s_ws)
{
  const int o  = blockIdx.x*256 + threadIdx.x;
  const int bt = blockIdx.y;
  float v = ab[o] + 1.0f;
  #pragma unroll
  for (int kp=0; kp<12; kp++)
    v += partial[((size_t)kp*128 + bt)*C3 + o];
  s_ws[(size_t)bt*C3 + o] = v;
}

// ---------------------------------------------------------------------------
// gemm4: double-buffered 2-phase pipeline.
// per (bt,g,mt): Out = (W_g .* s) x X^T. Tile 128x208, BK=32, 24 K-steps.
// ---------------------------------------------------------------------------
__global__ __launch_bounds__(256)
void gemm4(const ushort* __restrict__ wbf, const ushort* __restrict__ xbf,
           const float* __restrict__ s_ws, const float* __restrict__ bias,
           float* __restrict__ out)
{
  __shared__ __align__(16) ushort A_lds[2][128*BK];
  __shared__ __align__(16) ushort B_lds[2][208*BK];

  // bijective XCD swizzle: 2304 = 8 * 288
  const int lid  = blockIdx.x;
  const int work = (lid & 7)*288 + (lid >> 3);
  const int bt   = work / 18;
  const int rem  = work - bt*18;
  const int g    = rem / 6;
  const int mt   = rem - g*6;

  const int tid = threadIdx.x, w = tid >> 6, lane = tid & 63;
  const int l15 = lane & 15, lq = lane >> 4;

  const float*  srow = s_ws + (size_t)bt*C3 + (size_t)g*C;
  const ushort* Ap   = wbf + ((size_t)g*C + (size_t)mt*128)*C;
  const ushort* xb   = xbf + (size_t)bt*NTOK*C;

  const int arow = tid >> 1;
  const int acol = (tid & 1) * 16;
  const ushort* awp = Ap + (size_t)arow*C + acol;
  const float*  asp = srow + acol;
  const int brow = lane >> 2;          // glds: lane -> row-in-16, chunk
  const int bcol = (lane & 3) * 8;

  f32x4 acc[2][13];
  #pragma unroll
  for (int i=0;i<2;i++)
    #pragma unroll
    for (int j=0;j<13;j++) acc[i][j] = (f32x4){0.f,0.f,0.f,0.f};

  // ---- prologue: fill buffer 0
  {
    uint4 w0 = *reinterpret_cast<const uint4*>(awp);
    uint4 w1 = *reinterpret_cast<const uint4*>(awp + 8);
    float4 s0 = *reinterpret_cast<const float4*>(asp);
    float4 s1 = *reinterpret_cast<const float4*>(asp+4);
    float4 s2 = *reinterpret_cast<const float4*>(asp+8);
    float4 s3 = *reinterpret_cast<const float4*>(asp+12);
    for (int e = w; e < 13; e += 4)
      glds16(&B_lds[0][e*512], xb + (size_t)(e*16 + brow)*C + bcol);
    uint4 o0, o1;
    o0.x = pack2(bfu2f(w0.x&0xffffu)*s0.x, bfu2f(w0.x>>16)*s0.y);
    o0.y = pack2(bfu2f(w0.y&0xffffu)*s0.z, bfu2f(w0.y>>16)*s0.w);
    o0.z = pack2(bfu2f(w0.z&0xffffu)*s1.x, bfu2f(w0.z>>16)*s1.y);
    o0.w = pack2(bfu2f(w0.w&0xffffu)*s1.z, bfu2f(w0.w>>16)*s1.w);
    o1.x = pack2(bfu2f(w1.x&0xffffu)*s2.x, bfu2f(w1.x>>16)*s2.y);
    o1.y = pack2(bfu2f(w1.y&0xffffu)*s2.z, bfu2f(w1.y>>16)*s2.w);
    o1.z = pack2(bfu2f(w1.z&0xffffu)*s3.x, bfu2f(w1.z>>16)*s3.y);
    o1.w = pack2(bfu2f(w1.w&0xffffu)*s3.z, bfu2f(w1.w>>16)*s3.w);
    *reinterpret_cast<uint4*>(&A_lds[0][arow*BK + acol    ]) = o0;
    *reinterpret_cast<uint4*>(&A_lds[0][arow*BK + acol + 8]) = o1;
  }
  __syncthreads();

  // ---- main loop
  for (int t = 0; t < 24; ++t){
    const int cur = t & 1, nxt = cur ^ 1;
    const int kn = t*BK + BK;
    uint4 w0, w1; float4 s0, s1, s2, s3;
    if (t < 23){
      // issue A loads FIRST (so convert's waitcnt leaves glds in flight)
      w0 = *reinterpret_cast<const uint4*>(awp + kn);
      w1 = *reinterpret_cast<const uint4*>(awp + kn + 8);
      s0 = *reinterpret_cast<const float4*>(asp + kn);
      s1 = *reinterpret_cast<const float4*>(asp + kn + 4);
      s2 = *reinterpret_cast<const float4*>(asp + kn + 8);
      s3 = *reinterpret_cast<const float4*>(asp + kn + 12);
      for (int e = w; e < 13; e += 4)
        glds16(&B_lds[nxt][e*512], xb + (size_t)(e*16 + brow)*C + kn + bcol);
    }

    // compute on buffer cur
    bf16x8 a0 = *reinterpret_cast<const bf16x8*>(&A_lds[cur][(w*32      + l15)*BK + lq*8]);
    bf16x8 a1 = *reinterpret_cast<const bf16x8*>(&A_lds[cur][(w*32 + 16 + l15)*BK + lq*8]);
    #pragma unroll
    for (int nf=0; nf<13; nf++){
      bf16x8 b = *reinterpret_cast<const bf16x8*>(&B_lds[cur][(nf*16 + l15)*BK + lq*8]);
      acc[0][nf] = __builtin_amdgcn_mfma_f32_16x16x32_bf16(a0, b, acc[0][nf], 0, 0, 0);
      acc[1][nf] = __builtin_amdgcn_mfma_f32_16x16x32_bf16(a1, b, acc[1][nf], 0, 0, 0);
    }

    if (t < 23){
      uint4 o0, o1;
      o0.x = pack2(bfu2f(w0.x&0xffffu)*s0.x, bfu2f(w0.x>>16)*s0.y);
      o0.y = pack2(bfu2f(w0.y&0xffffu)*s0.z, bfu2f(w0.y>>16)*s0.w);
      o0.z = pack2(bfu2f(w0.z&0xffffu)*s1.x, bfu2f(w0.z>>16)*s1.y);
      o0.w = pack2(bfu2f(w0.w&0xffffu)*s1.z, bfu2f(w0.w>>16)*s1.w);
      o1.x = pack2(bfu2f(w1.x&0xffffu)*s2.x, bfu2f(w1.x>>16)*s2.y);
      o1.y = pack2(bfu2f(w1.y&0xffffu)*s2.z, bfu2f(w1.y>>16)*s2.w);
      o1.z = pack2(bfu2f(w1.z&0xffffu)*s3.x, bfu2f(w1.z>>16)*s3.y);
      o1.w = pack2(bfu2f(w1.w&0xffffu)*s3.z, bfu2f(w1.w>>16)*s3.w);
      *reinterpret_cast<uint4*>(&A_lds[nxt][arow*BK + acol    ]) = o0;
      *reinterpret_cast<uint4*>(&A_lds[nxt][arow*BK + acol + 8]) = o1;
      __syncthreads();   // drains vmcnt (glds) + lgkm (ds_write): buffer nxt ready
    }
  }

  // ---- epilogue
  #pragma unroll
  for (int mf=0; mf<2; mf++){
    const int o0 = mt*128 + w*32 + mf*16 + lq*4;
    float bs[4];
    #pragma unroll
    for (int r=0;r<4;r++)
      bs[r] = bias[g*C + o0 + r] * srow[o0 + r];
    #pragma unroll
    for (int nf=0; nf<13; nf++){
      int n = nf*16 + l15;
      if (n < NTOK){
        #pragma unroll
        for (int r=0;r<4;r++)
          out[((size_t)bt*C3 + g*C + o0 + r)*NTOK + n] = acc[mf][nf][r] + bs[r];
      }
    }
  }
}

// ---------------------------------------------------------------------------
// fallback path (never taken when ws >= NEED_FULL; kept as insurance)
// ---------------------------------------------------------------------------
__global__ __launch_bounds__(256)
void conv3(const float* __restrict__ x, const float* __restrict__ aw,
           const float* __restrict__ ab, float* __restrict__ s_ws)
{
  __shared__ __align__(16) float  cls[10][CPAD];
  __shared__ __align__(16) ushort awt[64*AWP];
  __shared__ float partial[64][4][9];
  const int oc = blockIdx.x, b = blockIdx.y, tid = threadIdx.x;

  for (int task = tid; task < 1920; task += 256){
    int row = task / 192, c4 = task % 192;
    float4 v = {0.f,0.f,0.f,0.f};
    if (row >= 1 && row <= 8)
      v = *reinterpret_cast<const float4*>(x + (size_t)(b*8 + row - 1)*NTOK*C + c4*4);
    *reinterpret_cast<float4*>(&cls[row][c4*4]) = v;
  }

  const int o_l = tid >> 2, part = tid & 3;
  float acc[8];
  #pragma unroll
  for (int t=0;t<8;t++) acc[t]=0.f;

  for (int it = 0; it < 12; ++it){
    const int i0 = it*64;
    #pragma unroll
    for (int j = 0; j < 12; ++j){
      int task = tid + j*256;
      int r = task / 48, c4 = task % 48;
      float4 v = *reinterpret_cast<const float4*>(aw + (size_t)(oc*64 + r)*C3 + i0*3 + c4*4);
      uint2 pk; pk.x = pack2(v.x, v.y); pk.y = pack2(v.z, v.w);
      *reinterpret_cast<uint2*>(&awt[r*AWP + c4*4]) = pk;
    }
    __syncthreads();

    #pragma unroll
    for (int qq = 0; qq < 4; ++qq){
      const int i_loc = part*16 + qq*4;
      const int ib = i0 + i_loc;
      float4 cv[10];
      #pragma unroll
      for (int t=0;t<10;t++) cv[t] = *reinterpret_cast<const float4*>(&cls[t][ib]);
      float wv[4][3];
      #pragma unroll
      for (int e=0;e<4;e++){
        #pragma unroll
        for (int dk=0;dk<3;dk++)
          wv[e][dk] = bfu2f((uint)awt[o_l*AWP + (i_loc+e)*3 + dk]);
      }
      #pragma unroll
      for (int e=0;e<4;e++){
        #pragma unroll
        for (int dk=0;dk<3;dk++){
          const float wf = wv[e][dk];
          #pragma unroll
          for (int t=0;t<8;t++){
            const float* cp = reinterpret_cast<const float*>(&cv[t+dk]);
            acc[t] += wf * cp[e];
          }
        }
      }
    }
    __syncthreads();
  }

  #pragma unroll
  for (int t=0;t<8;t++) partial[o_l][part][t] = acc[t];
  __syncthreads();

  for (int idx = tid; idx < 512; idx += 256){
    int o = idx >> 3, t = idx & 7;
    float v = partial[o][0][t] + partial[o][1][t]
            + partial[o][2][t] + partial[o][3][t]
            + ab[oc*64 + o] + 1.0f;
    s_ws[(size_t)(b*8 + t)*C3 + oc*64 + o] = v;
  }
}

__global__ __launch_bounds__(512)
void gemm_fb(const float* __restrict__ x, const ushort* __restrict__ wbf,
             const float* __restrict__ s_ws, const float* __restrict__ bias,
             float* __restrict__ out)
{
  __shared__ __align__(16) ushort A_lds[128*PK];
  __shared__ __align__(16) ushort B_lds[208*PK];
  const int ot  = blockIdx.x;
  const int g   = blockIdx.y;
  const int bt  = blockIdx.z;
  const int tid = threadIdx.x;
  const int w = tid >> 6, lane = tid & 63;
  const int l15 = lane & 15, lq = lane >> 4;

  const float*  srow  = s_ws + (size_t)bt*C3 + (size_t)g*C;
  const ushort* wrow  = wbf + ((size_t)g*C + (size_t)ot*128)*C;
  const float*  xrow  = x   + (size_t)bt*NTOK*C;

  f32x4 acc[NT];
  #pragma unroll
  for (int j=0;j<NT;j++) acc[j] = (f32x4){0.f,0.f,0.f,0.f};

  const int ar = tid >> 2, ac = tid & 3;

  for (int k0 = 0; k0 < C; k0 += BK){
    {
      uint4 wv = *reinterpret_cast<const uint4*>(wrow + (size_t)ar*C + k0 + ac*8);
      const float* sv = srow + k0 + ac*8;
      float4 s0 = *reinterpret_cast<const float4*>(sv);
      float4 s1 = *reinterpret_cast<const float4*>(sv+4);
      uint4 av;
      av.x = pack2(bfu2f(wv.x & 0xffffu)*s0.x, bfu2f(wv.x >> 16)*s0.y);
      av.y = pack2(bfu2f(wv.y & 0xffffu)*s0.z, bfu2f(wv.y >> 16)*s0.w);
      av.z = pack2(bfu2f(wv.z & 0xffffu)*s1.x, bfu2f(wv.z >> 16)*s1.y);
      av.w = pack2(bfu2f(wv.w & 0xffffu)*s1.z, bfu2f(wv.w >> 16)*s1.w);
      *reinterpret_cast<uint4*>(&A_lds[ar*PK + ac*8]) = av;
    }
    #pragma unroll
    for (int it = 0; it < 2; ++it){
      int task = tid + it*512;
      if (task < 832){
        int r = task >> 2, cc = task & 3;
        uint4 bv = {0u,0u,0u,0u};
        if (r < NTOK){
          const float* p = xrow + (size_t)r*C + k0 + cc*8;
          float4 lo = *reinterpret_cast<const float4*>(p);
          float4 hi = *reinterpret_cast<const float4*>(p+4);
          bv.x = pack2(lo.x, lo.y); bv.y = pack2(lo.z, lo.w);
          bv.z = pack2(hi.x, hi.y); bv.w = pack2(hi.z, hi.w);
        }
        *reinterpret_cast<uint4*>(&B_lds[r*PK + cc*8]) = bv;
      }
    }
    __syncthreads();

    bf16x8 a = *reinterpret_cast<const bf16x8*>(&A_lds[(w*16 + l15)*PK + lq*8]);
    #pragma unroll
    for (int j=0;j<NT;j++){
      bf16x8 b = *reinterpret_cast<const bf16x8*>(&B_lds[(j*16 + l15)*PK + lq*8]);
      acc[j] = __builtin_amdgcn_mfma_f32_16x16x32_bf16(a, b, acc[j], 0, 0, 0);
    }
    __syncthreads();
  }

  const int obase = ot*128 + w*16 + lq*4;
  float bs[4];
  #pragma unroll
  for (int r=0;r<4;r++)
    bs[r] = bias[g*C + obase + r] * srow[obase + r];
  #pragma unroll
  for (int j=0;j<NT;j++){
    int n = j*16 + l15;
    if (n < NTOK){
      #pragma unroll
      for (int r=0;r<4;r++)
        out[((size_t)bt*C3 + g*C + obase + r)*NTOK + n] = acc[j][r] + bs[r];
    }
  }
}

__global__ void cvt_w_only(const float* __restrict__ in, ushort* __restrict__ outp, int n4)
{
  int stride = gridDim.x * blockDim.x;
  for (int i = blockIdx.x*blockDim.x + threadIdx.x; i < n4; i += stride){
    float4 v = reinterpret_cast<const float4*>(in)[i];
    ushort4 o;
    o.x = f2bf(v.x); o.y = f2bf(v.y); o.z = f2bf(v.z); o.w = f2bf(v.w);
    reinterpret_cast<ushort4*>(outp)[i] = o;
  }
}

// ---------------------------------------------------------------------------
extern "C" void kernel_launch(void* const* d_in, const int* in_sizes, int n_in,
                              void* d_out, int out_size, void* d_ws, size_t ws_size,
                              hipStream_t stream)
{
  const float* x        = (const float*)d_in[0];
  const float* a_weight = (const float*)d_in[1];
  const float* a_bias   = (const float*)d_in[2];
  const float* weight   = (const float*)d_in[3];
  const float* bias     = (const float*)d_in[4];
  float* out = (float*)d_out;

  char* ws = (char*)d_ws;
  float*  s_ws = (float*)ws;                    // 1,179,648 B
  ushort* wbf  = (ushort*)(ws + 1179648);       // 3,538,944 B
  ushort* xbf  = (ushort*)(ws + 4718592);       // 38,731,776 B
  float*  part = (float*)(ws + 43450368);       // 14,155,776 B
  const size_t NEED_FULL = 57638912;            // incl. 32 KB OOB-read slack

  if (ws_size >= NEED_FULL){
    conv_part<<<dim3(36,12), 256, 0, stream>>>(x, a_weight, part);
    conv_reduce<<<dim3(9,128), 256, 0, stream>>>(part, a_bias, s_ws);
    cvt_all<<<dim3(2048), 256, 0, stream>>>(weight, x, wbf, xbf);
    gemm4<<<dim3(2304), 256, 0, stream>>>(wbf, xbf, s_ws, bias, out);
  } else {
    cvt_w_only<<<dim3(1728), 256, 0, stream>>>(weight, wbf, 442368);
    conv3<<<dim3(36,16), 256, 0, stream>>>(x, a_weight, a_bias, s_ws);
    gemm_fb<<<dim3(6,3,128), 512, 0, stream>>>(x, wbf, s_ws, bias, out);
  }
}

// Round 6
// 479.160 us; speedup vs baseline: 1.3579x; 1.0261x over previous
//
#include <hip/hip_runtime.h>

#define NTOK 197
#define C 768
#define C3 2304
#define BK 32
#define PKB 40    // padded B pitch (ushorts): bank stride 20 -> 2-way (free)
#define PK 40     // fallback LDS pitch
#define NT 13
#define CPAD 772  // fallback cls pitch
#define AWP 200   // fallback aw pitch

typedef __attribute__((ext_vector_type(4))) float f32x4;
typedef __attribute__((ext_vector_type(8))) short bf16x8;
typedef unsigned int u32;

__device__ __forceinline__ ushort f2bf(float f){
  uint u = __float_as_uint(f);
  u += 0x7fffu + ((u >> 16) & 1u);   // RNE
  return (ushort)(u >> 16);
}
__device__ __forceinline__ uint pack2(float a, float b){
  return (uint)f2bf(a) | ((uint)f2bf(b) << 16);
}
__device__ __forceinline__ float bfu2f(uint u){ return __uint_as_float(u << 16); }

__device__ __forceinline__ void glds16(ushort* lds, const ushort* gsrc){
  __builtin_amdgcn_global_load_lds((const __attribute__((address_space(1))) u32*)gsrc,
                                   (__attribute__((address_space(3))) u32*)lds, 16, 0, 0);
}

// ---------------------------------------------------------------------------
// cvt_all: weight then x -> bf16, branch-free grid-stride
// ---------------------------------------------------------------------------
#define N4_W 442368
#define N4_X 4841472
__global__ __launch_bounds__(256)
void cvt_all(const float* __restrict__ w, const float* __restrict__ x,
             ushort* __restrict__ wbf, ushort* __restrict__ xbf)
{
  const int tid0 = blockIdx.x*256 + threadIdx.x;
  const int stride = gridDim.x*256;
  for (int i = tid0; i < N4_W; i += stride){
    float4 v = reinterpret_cast<const float4*>(w)[i];
    ushort4 o; o.x=f2bf(v.x); o.y=f2bf(v.y); o.z=f2bf(v.z); o.w=f2bf(v.w);
    reinterpret_cast<ushort4*>(wbf)[i] = o;
  }
  for (int i = tid0; i < N4_X; i += stride){
    float4 v = reinterpret_cast<const float4*>(x)[i];
    ushort4 o; o.x=f2bf(v.x); o.y=f2bf(v.y); o.z=f2bf(v.z); o.w=f2bf(v.w);
    reinterpret_cast<ushort4*>(xbf)[i] = o;
  }
}

// ---------------------------------------------------------------------------
// conv_part: split-K routing conv. grid (36 oc, 12 kp), block 256 = 64 o x 4 bq.
// ---------------------------------------------------------------------------
__global__ __launch_bounds__(256)
void conv_part(const float* __restrict__ x, const float* __restrict__ aw,
               float* __restrict__ partial)
{
  __shared__ __align__(16) float  cls[16][10][68];
  __shared__ __align__(16) ushort awt[64*64*4];
  const int oc = blockIdx.x, kp = blockIdx.y, tid = threadIdx.x;
  const int k0 = kp*64;

  for (int task = tid; task < 2560; task += 256){
    int b = task / 160, rem = task % 160;
    int tp = rem / 16, c4 = rem % 16;
    float4 v = {0.f,0.f,0.f,0.f};
    if (tp >= 1 && tp <= 8)
      v = *reinterpret_cast<const float4*>(x + (size_t)(b*8 + tp - 1)*NTOK*C + k0 + c4*4);
    *reinterpret_cast<float4*>(&cls[b][tp][c4*4]) = v;
  }
  for (int task = tid; task < 1024; task += 256){
    int r = task >> 4, kc = task & 15;
    const float* p = aw + (size_t)(oc*64 + r)*2304 + (size_t)(k0 + kc*4)*3;
    float4 f0 = *reinterpret_cast<const float4*>(p);
    float4 f1 = *reinterpret_cast<const float4*>(p+4);
    float4 f2 = *reinterpret_cast<const float4*>(p+8);
    float f[12] = {f0.x,f0.y,f0.z,f0.w, f1.x,f1.y,f1.z,f1.w, f2.x,f2.y,f2.z,f2.w};
    uint4 o0, o1;
    o0.x = pack2(f[0], f[1]);  o0.y = (uint)f2bf(f[2]);
    o0.z = pack2(f[3], f[4]);  o0.w = (uint)f2bf(f[5]);
    o1.x = pack2(f[6], f[7]);  o1.y = (uint)f2bf(f[8]);
    o1.z = pack2(f[9], f[10]); o1.w = (uint)f2bf(f[11]);
    uint4* dst = reinterpret_cast<uint4*>(&awt[(r*64 + kc*4)*4]);
    dst[0] = o0; dst[1] = o1;
  }
  __syncthreads();

  const int o_l = tid >> 2, bq = tid & 3;
  float acc[8][4];
  #pragma unroll
  for (int t=0;t<8;t++)
    #pragma unroll
    for (int bi=0;bi<4;bi++) acc[t][bi]=0.f;

  #pragma unroll 1
  for (int kc = 0; kc < 16; ++kc){
    const uint4* ap = reinterpret_cast<const uint4*>(&awt[(o_l*64 + kc*4)*4]);
    uint4 aw0 = ap[0], aw1 = ap[1];
    float wv[4][3];
    wv[0][0]=bfu2f(aw0.x&0xffffu); wv[0][1]=bfu2f(aw0.x>>16); wv[0][2]=bfu2f(aw0.y&0xffffu);
    wv[1][0]=bfu2f(aw0.z&0xffffu); wv[1][1]=bfu2f(aw0.z>>16); wv[1][2]=bfu2f(aw0.w&0xffffu);
    wv[2][0]=bfu2f(aw1.x&0xffffu); wv[2][1]=bfu2f(aw1.x>>16); wv[2][2]=bfu2f(aw1.y&0xffffu);
    wv[3][0]=bfu2f(aw1.z&0xffffu); wv[3][1]=bfu2f(aw1.z>>16); wv[3][2]=bfu2f(aw1.w&0xffffu);
    #pragma unroll
    for (int bi=0; bi<4; ++bi){
      const int b = bq + 4*bi;
      float4 cv[10];
      #pragma unroll
      for (int tp=0; tp<10; tp++)
        cv[tp] = *reinterpret_cast<const float4*>(&cls[b][tp][kc*4]);
      #pragma unroll
      for (int t=0;t<8;t++){
        #pragma unroll
        for (int dk=0;dk<3;dk++){
          const float* cp = reinterpret_cast<const float*>(&cv[t+dk]);
          #pragma unroll
          for (int e=0;e<4;e++)
            acc[t][bi] += wv[e][dk] * cp[e];
        }
      }
    }
  }

  #pragma unroll
  for (int bi=0;bi<4;bi++){
    const int b = bq + 4*bi;
    #pragma unroll
    for (int t=0;t<8;t++)
      partial[((size_t)kp*128 + b*8 + t)*C3 + oc*64 + o_l] = acc[t][bi];
  }
}

// ---------------------------------------------------------------------------
// conv_reduce
// ---------------------------------------------------------------------------
__global__ __launch_bounds__(256)
void conv_reduce(const float* __restrict__ partial, const float* __restrict__ ab,
                 float* __restrict__ s_ws)
{
  const int o  = blockIdx.x*256 + threadIdx.x;
  const int bt = blockIdx.y;
  float v = ab[o] + 1.0f;
  #pragma unroll
  for (int kp=0; kp<12; kp++)
    v += partial[((size_t)kp*128 + bt)*C3 + o];
  s_ws[(size_t)bt*C3 + o] = v;
}

// ---------------------------------------------------------------------------
// gemm5: dbuf pipeline; A reg-staged+scaled (pitch 32), B reg-staged copy
// into PADDED pitch-40 LDS (conflict-free reads). One barrier per K-step.
// ---------------------------------------------------------------------------
__global__ __launch_bounds__(256)
void gemm5(const ushort* __restrict__ wbf, const ushort* __restrict__ xbf,
           const float* __restrict__ s_ws, const float* __restrict__ bias,
           float* __restrict__ out)
{
  __shared__ __align__(16) ushort A_lds[2][128*BK];    // 16 KB
  __shared__ __align__(16) ushort B_lds[2][208*PKB];   // 32.5 KB

  const int lid  = blockIdx.x;
  const int work = (lid & 7)*288 + (lid >> 3);
  const int bt   = work / 18;
  const int rem  = work - bt*18;
  const int g    = rem / 6;
  const int mt   = rem - g*6;

  const int tid = threadIdx.x, w = tid >> 6, lane = tid & 63;
  const int l15 = lane & 15, lq = lane >> 4;

  const float*  srow = s_ws + (size_t)bt*C3 + (size_t)g*C;
  const ushort* Ap   = wbf + ((size_t)g*C + (size_t)mt*128)*C;
  const ushort* xb   = xbf + (size_t)bt*NTOK*C;

  const int arow = tid >> 1;
  const int acol = (tid & 1) * 16;
  const ushort* awp = Ap + (size_t)arow*C + acol;
  const float*  asp = srow + acol;

  // B staging tasks: 832 uint4 (208 rows x 4 chunks); thread does 3 (+1 if tid<64)
  const int br0 = tid >> 2,            bc0 = (tid & 3) * 8;          // task tid
  const int br1 = (tid + 256) >> 2,    bc1 = bc0;                    // task tid+256
  const int br2 = (tid + 512) >> 2,    bc2 = bc0;                    // task tid+512
  const int br3 = 192 + (tid >> 2),    bc3 = bc0;                    // task tid+768 (tid<64)

  f32x4 acc[2][13];
  #pragma unroll
  for (int i=0;i<2;i++)
    #pragma unroll
    for (int j=0;j<13;j++) acc[i][j] = (f32x4){0.f,0.f,0.f,0.f};

  // ---- prologue: fill buffer 0 (k0 = 0)
  {
    uint4 w0 = *reinterpret_cast<const uint4*>(awp);
    uint4 w1 = *reinterpret_cast<const uint4*>(awp + 8);
    float4 s0 = *reinterpret_cast<const float4*>(asp);
    float4 s1 = *reinterpret_cast<const float4*>(asp+4);
    float4 s2 = *reinterpret_cast<const float4*>(asp+8);
    float4 s3 = *reinterpret_cast<const float4*>(asp+12);
    uint4 b0 = *reinterpret_cast<const uint4*>(xb + (size_t)br0*C + bc0);
    uint4 b1 = *reinterpret_cast<const uint4*>(xb + (size_t)br1*C + bc1);
    uint4 b2 = *reinterpret_cast<const uint4*>(xb + (size_t)br2*C + bc2);
    uint4 b3;
    if (tid < 64) b3 = *reinterpret_cast<const uint4*>(xb + (size_t)br3*C + bc3);

    uint4 o0, o1;
    o0.x = pack2(bfu2f(w0.x&0xffffu)*s0.x, bfu2f(w0.x>>16)*s0.y);
    o0.y = pack2(bfu2f(w0.y&0xffffu)*s0.z, bfu2f(w0.y>>16)*s0.w);
    o0.z = pack2(bfu2f(w0.z&0xffffu)*s1.x, bfu2f(w0.z>>16)*s1.y);
    o0.w = pack2(bfu2f(w0.w&0xffffu)*s1.z, bfu2f(w0.w>>16)*s1.w);
    o1.x = pack2(bfu2f(w1.x&0xffffu)*s2.x, bfu2f(w1.x>>16)*s2.y);
    o1.y = pack2(bfu2f(w1.y&0xffffu)*s2.z, bfu2f(w1.y>>16)*s2.w);
    o1.z = pack2(bfu2f(w1.z&0xffffu)*s3.x, bfu2f(w1.z>>16)*s3.y);
    o1.w = pack2(bfu2f(w1.w&0xffffu)*s3.z, bfu2f(w1.w>>16)*s3.w);
    *reinterpret_cast<uint4*>(&A_lds[0][arow*BK + acol    ]) = o0;
    *reinterpret_cast<uint4*>(&A_lds[0][arow*BK + acol + 8]) = o1;
    *reinterpret_cast<uint4*>(&B_lds[0][br0*PKB + bc0]) = b0;
    *reinterpret_cast<uint4*>(&B_lds[0][br1*PKB + bc1]) = b1;
    *reinterpret_cast<uint4*>(&B_lds[0][br2*PKB + bc2]) = b2;
    if (tid < 64)
      *reinterpret_cast<uint4*>(&B_lds[0][br3*PKB + bc3]) = b3;
  }
  __syncthreads();

  // ---- main loop
  for (int t = 0; t < 24; ++t){
    const int cur = t & 1, nxt = cur ^ 1;
    const int kn = t*BK + BK;
    uint4 w0, w1; float4 s0, s1, s2, s3;
    uint4 b0, b1, b2, b3;
    if (t < 23){
      // issue next-tile loads first; results consumed after MFMA
      w0 = *reinterpret_cast<const uint4*>(awp + kn);
      w1 = *reinterpret_cast<const uint4*>(awp + kn + 8);
      s0 = *reinterpret_cast<const float4*>(asp + kn);
      s1 = *reinterpret_cast<const float4*>(asp + kn + 4);
      s2 = *reinterpret_cast<const float4*>(asp + kn + 8);
      s3 = *reinterpret_cast<const float4*>(asp + kn + 12);
      b0 = *reinterpret_cast<const uint4*>(xb + (size_t)br0*C + kn + bc0);
      b1 = *reinterpret_cast<const uint4*>(xb + (size_t)br1*C + kn + bc1);
      b2 = *reinterpret_cast<const uint4*>(xb + (size_t)br2*C + kn + bc2);
      if (tid < 64) b3 = *reinterpret_cast<const uint4*>(xb + (size_t)br3*C + kn + bc3);
    }

    // compute on buffer cur
    bf16x8 a0 = *reinterpret_cast<const bf16x8*>(&A_lds[cur][(w*32      + l15)*BK + lq*8]);
    bf16x8 a1 = *reinterpret_cast<const bf16x8*>(&A_lds[cur][(w*32 + 16 + l15)*BK + lq*8]);
    #pragma unroll
    for (int nf=0; nf<13; nf++){
      bf16x8 b = *reinterpret_cast<const bf16x8*>(&B_lds[cur][(nf*16 + l15)*PKB + lq*8]);
      acc[0][nf] = __builtin_amdgcn_mfma_f32_16x16x32_bf16(a0, b, acc[0][nf], 0, 0, 0);
      acc[1][nf] = __builtin_amdgcn_mfma_f32_16x16x32_bf16(a1, b, acc[1][nf], 0, 0, 0);
    }

    if (t < 23){
      uint4 o0, o1;
      o0.x = pack2(bfu2f(w0.x&0xffffu)*s0.x, bfu2f(w0.x>>16)*s0.y);
      o0.y = pack2(bfu2f(w0.y&0xffffu)*s0.z, bfu2f(w0.y>>16)*s0.w);
      o0.z = pack2(bfu2f(w0.z&0xffffu)*s1.x, bfu2f(w0.z>>16)*s1.y);
      o0.w = pack2(bfu2f(w0.w&0xffffu)*s1.z, bfu2f(w0.w>>16)*s1.w);
      o1.x = pack2(bfu2f(w1.x&0xffffu)*s2.x, bfu2f(w1.x>>16)*s2.y);
      o1.y = pack2(bfu2f(w1.y&0xffffu)*s2.z, bfu2f(w1.y>>16)*s2.w);
      o1.z = pack2(bfu2f(w1.z&0xffffu)*s3.x, bfu2f(w1.z>>16)*s3.y);
      o1.w = pack2(bfu2f(w1.w&0xffffu)*s3.z, bfu2f(w1.w>>16)*s3.w);
      *reinterpret_cast<uint4*>(&A_lds[nxt][arow*BK + acol    ]) = o0;
      *reinterpret_cast<uint4*>(&A_lds[nxt][arow*BK + acol + 8]) = o1;
      *reinterpret_cast<uint4*>(&B_lds[nxt][br0*PKB + bc0]) = b0;
      *reinterpret_cast<uint4*>(&B_lds[nxt][br1*PKB + bc1]) = b1;
      *reinterpret_cast<uint4*>(&B_lds[nxt][br2*PKB + bc2]) = b2;
      if (tid < 64)
        *reinterpret_cast<uint4*>(&B_lds[nxt][br3*PKB + bc3]) = b3;
      __syncthreads();
    }
  }

  // ---- epilogue
  #pragma unroll
  for (int mf=0; mf<2; mf++){
    const int o0 = mt*128 + w*32 + mf*16 + lq*4;
    float bs[4];
    #pragma unroll
    for (int r=0;r<4;r++)
      bs[r] = bias[g*C + o0 + r] * srow[o0 + r];
    #pragma unroll
    for (int nf=0; nf<13; nf++){
      int n = nf*16 + l15;
      if (n < NTOK){
        #pragma unroll
        for (int r=0;r<4;r++)
          out[((size_t)bt*C3 + g*C + o0 + r)*NTOK + n] = acc[mf][nf][r] + bs[r];
      }
    }
  }
}

// ---------------------------------------------------------------------------
// fallback path (insurance only)
// ---------------------------------------------------------------------------
__global__ __launch_bounds__(256)
void conv3(const float* __restrict__ x, const float* __restrict__ aw,
           const float* __restrict__ ab, float* __restrict__ s_ws)
{
  __shared__ __align__(16) float  cls[10][CPAD];
  __shared__ __align__(16) ushort awt[64*AWP];
  __shared__ float partial[64][4][9];
  const int oc = blockIdx.x, b = blockIdx.y, tid = threadIdx.x;

  for (int task = tid; task < 1920; task += 256){
    int row = task / 192, c4 = task % 192;
    float4 v = {0.f,0.f,0.f,0.f};
    if (row >= 1 && row <= 8)
      v = *reinterpret_cast<const float4*>(x + (size_t)(b*8 + row - 1)*NTOK*C + c4*4);
    *reinterpret_cast<float4*>(&cls[row][c4*4]) = v;
  }

  const int o_l = tid >> 2, part = tid & 3;
  float acc[8];
  #pragma unroll
  for (int t=0;t<8;t++) acc[t]=0.f;

  for (int it = 0; it < 12; ++it){
    const int i0 = it*64;
    #pragma unroll
    for (int j = 0; j < 12; ++j){
      int task = tid + j*256;
      int r = task / 48, c4 = task % 48;
      float4 v = *reinterpret_cast<const float4*>(aw + (size_t)(oc*64 + r)*C3 + i0*3 + c4*4);
      uint2 pk; pk.x = pack2(v.x, v.y); pk.y = pack2(v.z, v.w);
      *reinterpret_cast<uint2*>(&awt[r*AWP + c4*4]) = pk;
    }
    __syncthreads();

    #pragma unroll
    for (int qq = 0; qq < 4; ++qq){
      const int i_loc = part*16 + qq*4;
      const int ib = i0 + i_loc;
      float4 cv[10];
      #pragma unroll
      for (int t=0;t<10;t++) cv[t] = *reinterpret_cast<const float4*>(&cls[t][ib]);
      float wv[4][3];
      #pragma unroll
      for (int e=0;e<4;e++){
        #pragma unroll
        for (int dk=0;dk<3;dk++)
          wv[e][dk] = bfu2f((uint)awt[o_l*AWP + (i_loc+e)*3 + dk]);
      }
      #pragma unroll
      for (int e=0;e<4;e++){
        #pragma unroll
        for (int dk=0;dk<3;dk++){
          const float wf = wv[e][dk];
          #pragma unroll
          for (int t=0;t<8;t++){
            const float* cp = reinterpret_cast<const float*>(&cv[t+dk]);
            acc[t] += wf * cp[e];
          }
        }
      }
    }
    __syncthreads();
  }

  #pragma unroll
  for (int t=0;t<8;t++) partial[o_l][part][t] = acc[t];
  __syncthreads();

  for (int idx = tid; idx < 512; idx += 256){
    int o = idx >> 3, t = idx & 7;
    float v = partial[o][0][t] + partial[o][1][t]
            + partial[o][2][t] + partial[o][3][t]
            + ab[oc*64 + o] + 1.0f;
    s_ws[(size_t)(b*8 + t)*C3 + oc*64 + o] = v;
  }
}

__global__ __launch_bounds__(512)
void gemm_fb(const float* __restrict__ x, const ushort* __restrict__ wbf,
             const float* __restrict__ s_ws, const float* __restrict__ bias,
             float* __restrict__ out)
{
  __shared__ __align__(16) ushort A_lds[128*PK];
  __shared__ __align__(16) ushort B_lds[208*PK];
  const int ot  = blockIdx.x;
  const int g   = blockIdx.y;
  const int bt  = blockIdx.z;
  const int tid = threadIdx.x;
  const int w = tid >> 6, lane = tid & 63;
  const int l15 = lane & 15, lq = lane >> 4;

  const float*  srow  = s_ws + (size_t)bt*C3 + (size_t)g*C;
  const ushort* wrow  = wbf + ((size_t)g*C + (size_t)ot*128)*C;
  const float*  xrow  = x   + (size_t)bt*NTOK*C;

  f32x4 acc[NT];
  #pragma unroll
  for (int j=0;j<NT;j++) acc[j] = (f32x4){0.f,0.f,0.f,0.f};

  const int ar = tid >> 2, ac = tid & 3;

  for (int k0 = 0; k0 < C; k0 += BK){
    {
      uint4 wv = *reinterpret_cast<const uint4*>(wrow + (size_t)ar*C + k0 + ac*8);
      const float* sv = srow + k0 + ac*8;
      float4 s0 = *reinterpret_cast<const float4*>(sv);
      float4 s1 = *reinterpret_cast<const float4*>(sv+4);
      uint4 av;
      av.x = pack2(bfu2f(wv.x & 0xffffu)*s0.x, bfu2f(wv.x >> 16)*s0.y);
      av.y = pack2(bfu2f(wv.y & 0xffffu)*s0.z, bfu2f(wv.y >> 16)*s0.w);
      av.z = pack2(bfu2f(wv.z & 0xffffu)*s1.x, bfu2f(wv.z >> 16)*s1.y);
      av.w = pack2(bfu2f(wv.w & 0xffffu)*s1.z, bfu2f(wv.w >> 16)*s1.w);
      *reinterpret_cast<uint4*>(&A_lds[ar*PK + ac*8]) = av;
    }
    #pragma unroll
    for (int it = 0; it < 2; ++it){
      int task = tid + it*512;
      if (task < 832){
        int r = task >> 2, cc = task & 3;
        uint4 bv = {0u,0u,0u,0u};
        if (r < NTOK){
          const float* p = xrow + (size_t)r*C + k0 + cc*8;
          float4 lo = *reinterpret_cast<const float4*>(p);
          float4 hi = *reinterpret_cast<const float4*>(p+4);
          bv.x = pack2(lo.x, lo.y); bv.y = pack2(lo.z, lo.w);
          bv.z = pack2(hi.x, hi.y); bv.w = pack2(hi.z, hi.w);
        }
        *reinterpret_cast<uint4*>(&B_lds[r*PK + cc*8]) = bv;
      }
    }
    __syncthreads();

    bf16x8 a = *reinterpret_cast<const bf16x8*>(&A_lds[(w*16 + l15)*PK + lq*8]);
    #pragma unroll
    for (int j=0;j<NT;j++){
      bf16x8 b = *reinterpret_cast<const bf16x8*>(&B_lds[(j*16 + l15)*PK + lq*8]);
      acc[j] = __builtin_amdgcn_mfma_f32_16x16x32_bf16(a, b, acc[j], 0, 0, 0);
    }
    __syncthreads();
  }

  const int obase = ot*128 + w*16 + lq*4;
  float bs[4];
  #pragma unroll
  for (int r=0;r<4;r++)
    bs[r] = bias[g*C + obase + r] * srow[obase + r];
  #pragma unroll
  for (int j=0;j<NT;j++){
    int n = j*16 + l15;
    if (n < NTOK){
      #pragma unroll
      for (int r=0;r<4;r++)
        out[((size_t)bt*C3 + g*C + obase + r)*NTOK + n] = acc[j][r] + bs[r];
    }
  }
}

__global__ void cvt_w_only(const float* __restrict__ in, ushort* __restrict__ outp, int n4)
{
  int stride = gridDim.x * blockDim.x;
  for (int i = blockIdx.x*blockDim.x + threadIdx.x; i < n4; i += stride){
    float4 v = reinterpret_cast<const float4*>(in)[i];
    ushort4 o;
    o.x = f2bf(v.x); o.y = f2bf(v.y); o.z = f2bf(v.z); o.w = f2bf(v.w);
    reinterpret_cast<ushort4*>(outp)[i] = o;
  }
}

// ---------------------------------------------------------------------------
extern "C" void kernel_launch(void* const* d_in, const int* in_sizes, int n_in,
                              void* d_out, int out_size, void* d_ws, size_t ws_size,
                              hipStream_t stream)
{
  const float* x        = (const float*)d_in[0];
  const float* a_weight = (const float*)d_in[1];
  const float* a_bias   = (const float*)d_in[2];
  const float* weight   = (const float*)d_in[3];
  const float* bias     = (const float*)d_in[4];
  float* out = (float*)d_out;

  char* ws = (char*)d_ws;
  float*  s_ws = (float*)ws;                    // 1,179,648 B
  ushort* wbf  = (ushort*)(ws + 1179648);       // 3,538,944 B
  ushort* xbf  = (ushort*)(ws + 4718592);       // 38,731,776 B
  float*  part = (float*)(ws + 43450368);       // 14,155,776 B (also OOB-read slack)
  const size_t NEED_FULL = 57638912;

  if (ws_size >= NEED_FULL){
    conv_part<<<dim3(36,12), 256, 0, stream>>>(x, a_weight, part);
    conv_reduce<<<dim3(9,128), 256, 0, stream>>>(part, a_bias, s_ws);
    cvt_all<<<dim3(2048), 256, 0, stream>>>(weight, x, wbf, xbf);
    gemm5<<<dim3(2304), 256, 0, stream>>>(wbf, xbf, s_ws, bias, out);
  } else {
    cvt_w_only<<<dim3(1728), 256, 0, stream>>>(weight, wbf, 442368);
    conv3<<<dim3(36,16), 256, 0, stream>>>(x, a_weight, a_bias, s_ws);
    gemm_fb<<<dim3(6,3,128), 512, 0, stream>>>(x, wbf, s_ws, bias, out);
  }
}